// Round 4
// baseline (233.784 us; speedup 1.0000x reference)
//
#include <hip/hip_runtime.h>
#include <hip/hip_bf16.h>

#define CCH   512
#define BATCH 8
#define NPOS  1024
#define MQKV  1536
#define EPS   1e-5f

typedef __attribute__((ext_vector_type(4))) float f32x4;
typedef __attribute__((ext_vector_type(8))) __bf16 bf16x8;
typedef __attribute__((ext_vector_type(8))) unsigned short u16x8;
typedef __attribute__((ext_vector_type(4))) unsigned short u16x4;

__device__ inline unsigned short f2bf(float f) {
  __hip_bfloat16 h = __float2bfloat16(f);
  return __builtin_bit_cast(unsigned short, h);
}
__device__ inline float bf2f(unsigned short u) {
  return __bfloat162float(__builtin_bit_cast(__hip_bfloat16, u));
}

// LDS xor-swizzle (T2): ushort index within a [row][64] tile.
__device__ inline int sw(int row, int col) { return row * 64 + (col ^ ((row & 7) << 3)); }

// ---------------- 1. weights fp32 -> bf16 (q rows pre-scaled by 1/8) ----------------
__global__ void prep_weights(const float* __restrict__ wq, const float* __restrict__ wo,
                             unsigned short* __restrict__ wqb, unsigned short* __restrict__ wob) {
  int i = blockIdx.x * 256 + threadIdx.x;
  if (i < MQKV * CCH) {
    float v = wq[i];
    if (i < 512 * CCH) v *= 0.125f;   // fold DIM_HEAD^-0.5 into q projection (exact: 2^-3)
    wqb[i] = f2bf(v);
  }
  if (i < CCH * CCH) wob[i] = f2bf(wo[i]);
}

// ---------------- 2. CPB table: [8][63][63] ----------------
__global__ void cpb_table(const float* __restrict__ w0, const float* __restrict__ b0,
                          const float* __restrict__ w1, const float* __restrict__ b1,
                          const float* __restrict__ w2, const float* __restrict__ b2,
                          float* __restrict__ table) {
  __shared__ float sh1[128];
  __shared__ float sh2[128];
  int d0 = blockIdx.x;               // 0..3968
  int dy = d0 / 63 - 31, dx = d0 % 63 - 31;
  float r0 = (dy > 0 ? 1.f : (dy < 0 ? -1.f : 0.f)) * logf(fabsf((float)dy) + 1.f);
  float r1 = (dx > 0 ? 1.f : (dx < 0 ? -1.f : 0.f)) * logf(fabsf((float)dx) + 1.f);
  int t = threadIdx.x;               // 128
  float h0 = r0 * w0[t * 2 + 0] + r1 * w0[t * 2 + 1] + b0[t];
  sh1[t] = (h0 >= 0.f) ? h0 : 0.1f * h0;
  __syncthreads();
  float a = b1[t];
  #pragma unroll 8
  for (int c = 0; c < 128; ++c) a += sh1[c] * w1[t * 128 + c];
  sh2[t] = (a >= 0.f) ? a : 0.1f * a;
  __syncthreads();
  if (t < 8) {
    float o = b2[t];
    #pragma unroll 8
    for (int c = 0; c < 128; ++c) o += sh2[c] * w2[t * 128 + c];
    table[t * 3969 + d0] = o;
  }
}

// ---------------- 3. expand bias, fragment-permuted: [h][i][jtile(16)][l16*4+jt] ----------------
__global__ void bias_expand(const float* __restrict__ table, unsigned short* __restrict__ biasP) {
  int idx = blockIdx.x * 256 + threadIdx.x;   // 8*1024*1024 total, idx == output address
  int h = idx >> 20;
  int i = (idx >> 10) & 1023;
  int blk = (idx >> 6) & 15;
  int q = idx & 63;
  int l16 = q >> 2, jt = q & 3;
  int j = blk * 64 + jt * 16 + l16;
  int dy = (i >> 5) - (j >> 5) + 31;
  int dx = (i & 31) - (j & 31) + 31;
  biasP[idx] = f2bf(table[h * 3969 + dy * 63 + dx]);
}

// ---------------- 4. channel LayerNorm -> xnT [8192][512] bf16 ----------------
__global__ __launch_bounds__(256) void ln_kernel(const float* __restrict__ x,
                                                 const float* __restrict__ gamma,
                                                 unsigned short* __restrict__ xnT) {
  int t = threadIdx.x;
  int gpos = blockIdx.x * 32 + (t >> 3);      // global position 0..8191
  int b = gpos >> 10, p = gpos & 1023;
  int cl = t & 7;
  const float* xp = x + (size_t)b * CCH * NPOS + p;
  float vals[64];
  float s1 = 0.f, s2 = 0.f;
  #pragma unroll
  for (int j = 0; j < 64; ++j) {
    float v = xp[(size_t)(cl * 64 + j) * NPOS];
    vals[j] = v; s1 += v; s2 += v * v;
  }
  #pragma unroll
  for (int m = 1; m < 8; m <<= 1) { s1 += __shfl_xor(s1, m, 64); s2 += __shfl_xor(s2, m, 64); }
  float mean = s1 * (1.f / 512.f);
  float var = s2 * (1.f / 512.f) - mean * mean;
  float rstd = rsqrtf(var + EPS);
  unsigned short outv[64];
  #pragma unroll
  for (int j = 0; j < 64; ++j) {
    int c = cl * 64 + j;
    outv[j] = f2bf((vals[j] - mean) * rstd * gamma[c]);
  }
  unsigned short* op = xnT + (size_t)gpos * 512 + cl * 64;
  #pragma unroll
  for (int j = 0; j < 8; ++j) *(u16x8*)(op + j * 8) = *(const u16x8*)(outv + j * 8);
}

// ---------------- 5. GEMM C = A * B^T, A[M][512], B[N][512] bf16 ----------------
// MODE 0: qkv epilogue (LDS-bounced coalesced scatter to qT/kT/vB).
// MODE 1: out proj + residual -> f32.
template <int MODE>
__global__ __launch_bounds__(256) void gemm_bt(const unsigned short* __restrict__ Ag,
                                               const unsigned short* __restrict__ Bg,
                                               unsigned short* __restrict__ qT,
                                               unsigned short* __restrict__ kT,
                                               unsigned short* __restrict__ vB,
                                               const float* __restrict__ xres,
                                               float* __restrict__ yout) {
  __shared__ unsigned short smem[2 * 128 * 64];   // As | Bs; reused as 128x128 C-tile
  unsigned short* As = smem;
  unsigned short* Bs = smem + 128 * 64;
  int tid = threadIdx.x;
  int m0 = blockIdx.y * 128, nn0 = blockIdx.x * 128;
  int wave = tid >> 6, lane = tid & 63;
  int wm = wave >> 1, wn = wave & 1;
  int l16 = lane & 15, lh = lane >> 4;
  f32x4 acc[4][4];
  #pragma unroll
  for (int it = 0; it < 4; ++it)
    #pragma unroll
    for (int jt = 0; jt < 4; ++jt) acc[it][jt] = (f32x4){0.f, 0.f, 0.f, 0.f};

  for (int k0 = 0; k0 < 512; k0 += 64) {
    #pragma unroll
    for (int r = 0; r < 4; ++r) {
      int li = r * 2048 + tid * 8;
      int row = li >> 6, col = li & 63;
      *(u16x8*)&As[sw(row, col)] = *(const u16x8*)&Ag[(size_t)(m0 + row) * 512 + k0 + col];
      *(u16x8*)&Bs[sw(row, col)] = *(const u16x8*)&Bg[(size_t)(nn0 + row) * 512 + k0 + col];
    }
    __syncthreads();
    #pragma unroll
    for (int ks = 0; ks < 2; ++ks) {
      int koff = ks * 32 + lh * 8;
      bf16x8 a[4], b[4];
      #pragma unroll
      for (int it = 0; it < 4; ++it) a[it] = *(const bf16x8*)&As[sw(wm * 64 + it * 16 + l16, koff)];
      #pragma unroll
      for (int jt = 0; jt < 4; ++jt) b[jt] = *(const bf16x8*)&Bs[sw(wn * 64 + jt * 16 + l16, koff)];
      #pragma unroll
      for (int it = 0; it < 4; ++it)
        #pragma unroll
        for (int jt = 0; jt < 4; ++jt)
          acc[it][jt] = __builtin_amdgcn_mfma_f32_16x16x32_bf16(a[it], b[jt], acc[it][jt], 0, 0, 0);
    }
    __syncthreads();
  }

  if (MODE == 1) {
    #pragma unroll
    for (int it = 0; it < 4; ++it) {
      int mbase = m0 + wm * 64 + it * 16 + lh * 4;
      #pragma unroll
      for (int jt = 0; jt < 4; ++jt) {
        int nn = nn0 + wn * 64 + jt * 16 + l16;
        int bb = nn >> 10, p = nn & 1023;
        #pragma unroll
        for (int r = 0; r < 4; ++r) {
          size_t addr = ((size_t)bb * 512 + mbase + r) * 1024 + p;
          yout[addr] = acc[it][jt][r] + xres[addr];
        }
      }
    }
  } else {
    // ---- LDS-bounced coalesced epilogue ----
    int by = blockIdx.y;
    int sel = by >> 2;                 // 0:q 1:k 2:v (m0 = by*128, 512 rows per sel)
    int hh0 = (by & 3) * 2;            // first of the two local heads in this m-block
    int bb = nn0 >> 10, p0 = nn0 & 1023;
    unsigned short* Cs = smem;         // 128x128 ushort = 32 KB
    if (sel < 2) {
      // transposed store: Cs[nn][m^k(nn)] so d (part of m) is contiguous on read
      #pragma unroll
      for (int it = 0; it < 4; ++it)
        #pragma unroll
        for (int jt = 0; jt < 4; ++jt) {
          int nnl = wn * 64 + jt * 16 + l16;
          int mb = wm * 64 + it * 16 + lh * 4;
          #pragma unroll
          for (int r = 0; r < 4; ++r)
            Cs[nnl * 128 + ((mb + r) ^ ((nnl & 7) << 4))] = f2bf(acc[it][jt][r]);
        }
      __syncthreads();
      unsigned short* dst = (sel == 0) ? qT : kT;
      // 2048 chunks of 8 ushort: c = [hl(1)][p(7)][ch(3)]
      #pragma unroll
      for (int i = 0; i < 8; ++i) {
        int c = tid + i * 256;
        int hl = c >> 10, p = (c >> 3) & 127, ch = c & 7;
        int mb = hl * 64 + ch * 8;
        u16x8 val = *(u16x8*)&Cs[p * 128 + (mb ^ ((p & 7) << 4))];
        int bh = bb * 8 + hh0 + hl;
        *(u16x8*)&dst[((size_t)bh * 1024 + p0 + p) * 64 + ch * 8] = val;
      }
    } else {
      // row-major store: Cs[m][nn^k(m)] so p (= nn) is contiguous on read
      #pragma unroll
      for (int it = 0; it < 4; ++it)
        #pragma unroll
        for (int jt = 0; jt < 4; ++jt) {
          int nnl = wn * 64 + jt * 16 + l16;
          int mb = wm * 64 + it * 16 + lh * 4;
          #pragma unroll
          for (int r = 0; r < 4; ++r)
            Cs[(mb + r) * 128 + (nnl ^ (((mb + r) & 7) << 4))] = f2bf(acc[it][jt][r]);
        }
      __syncthreads();
      // 2048 chunks: c = [mloc(7)][ch(4)]
      #pragma unroll
      for (int i = 0; i < 8; ++i) {
        int c = tid + i * 256;
        int mloc = c >> 4, ch = c & 15;
        u16x8 val = *(u16x8*)&Cs[mloc * 128 + ((ch * 8) ^ ((mloc & 7) << 4))];
        int d = mloc & 63, hl = mloc >> 6;
        int bh = bb * 8 + hh0 + hl;
        *(u16x8*)&vB[((size_t)bh * 64 + d) * 1024 + p0 + ch * 8] = val;
      }
    }
  }
}

// ---------------- 6. flash attention, no LDS staging (K/V are L2-resident) ----------------
// grid (bh fastest -> 8 bh per XCD -> 2MB K/V working set per L2). No barriers at all.
__global__ __launch_bounds__(256, 4) void attn_kernel(const unsigned short* __restrict__ qT,
                                                      const unsigned short* __restrict__ kT,
                                                      const unsigned short* __restrict__ vB,
                                                      const unsigned short* __restrict__ biasP,
                                                      unsigned short* __restrict__ attnout) {
  __shared__ unsigned short Ps[4][16 * 64];
  int tid = threadIdx.x;
  int bh = blockIdx.x;               // fastest dim: round-robins XCDs by bh
  int i0 = blockIdx.y * 64;
  int hh = bh & 7, bb = bh >> 3;
  int w = tid >> 6, lane = tid & 63, l16 = lane & 15, lh = lane >> 4;

  // Q fragments in registers (one q-row per lane)
  int qrow = i0 + w * 16 + l16;
  const unsigned short* qb = qT + ((size_t)bh * NPOS + qrow) * 64 + lh * 8;
  bf16x8 qreg[2];
  qreg[0] = *(const bf16x8*)&qb[0];
  qreg[1] = *(const bf16x8*)&qb[32];

  const unsigned short* kptr = kT + (size_t)bh * NPOS * 64 + l16 * 64 + lh * 8;
  const unsigned short* vptr = vB + (size_t)bh * 64 * NPOS + l16 * 1024 + lh * 8;
  const unsigned short* bptr = biasP + (((size_t)hh * 1024 + i0 + w * 16) * 16) * 64 + l16 * 4;

  f32x4 o[5];                        // 0..3 output d-fragments, 4 = softmax denominator
  float m_s[4];
  #pragma unroll
  for (int dt = 0; dt < 5; ++dt) o[dt] = (f32x4){0.f, 0.f, 0.f, 0.f};
  #pragma unroll
  for (int r = 0; r < 4; ++r) m_s[r] = -1e30f;

  bf16x8 ones;
  {
    u16x8 tmp = {0x3F80, 0x3F80, 0x3F80, 0x3F80, 0x3F80, 0x3F80, 0x3F80, 0x3F80};
    ones = __builtin_bit_cast(bf16x8, tmp);
  }

  #pragma unroll 1
  for (int j0 = 0; j0 < 1024; j0 += 64) {
    // ---- load K and V fragments for this tile (L2-resident) ----
    bf16x8 bk[2][4], vv[2][4];
    #pragma unroll
    for (int ks = 0; ks < 2; ++ks)
      #pragma unroll
      for (int jt = 0; jt < 4; ++jt)
        bk[ks][jt] = *(const bf16x8*)&kptr[(j0 + jt * 16) * 64 + ks * 32];
    #pragma unroll
    for (int js = 0; js < 2; ++js)
      #pragma unroll
      for (int dt = 0; dt < 4; ++dt)
        vv[js][dt] = *(const bf16x8*)&vptr[(dt * 16) * 1024 + j0 + js * 32];

    // ---- QK^T ----
    f32x4 s[4];
    #pragma unroll
    for (int jt = 0; jt < 4; ++jt) s[jt] = (f32x4){0.f, 0.f, 0.f, 0.f};
    #pragma unroll
    for (int ks = 0; ks < 2; ++ks)
      #pragma unroll
      for (int jt = 0; jt < 4; ++jt)
        s[jt] = __builtin_amdgcn_mfma_f32_16x16x32_bf16(qreg[ks], bk[ks][jt], s[jt], 0, 0, 0);

    // ---- online softmax with defer-max (T13, THR=8) ----
    #pragma unroll
    for (int r = 0; r < 4; ++r) {
      int rloc = lh * 4 + r;
      u16x4 bv = *(const u16x4*)&bptr[rloc * 1024 + (j0 >> 6) * 64];
      float sv[4];
      #pragma unroll
      for (int jt = 0; jt < 4; ++jt) sv[jt] = s[jt][r] + bf2f(bv[jt]);
      float tmax = fmaxf(fmaxf(sv[0], sv[1]), fmaxf(sv[2], sv[3]));
      #pragma unroll
      for (int mm = 1; mm < 16; mm <<= 1) tmax = fmaxf(tmax, __shfl_xor(tmax, mm, 64));
      if (!__all(tmax <= m_s[r] + 8.0f)) {
        float mnew = fmaxf(m_s[r], tmax);
        float corr = __expf(m_s[r] - mnew);
        m_s[r] = mnew;
        #pragma unroll
        for (int dt = 0; dt < 5; ++dt) o[dt][r] *= corr;
      }
      #pragma unroll
      for (int jt = 0; jt < 4; ++jt)
        Ps[w][sw(rloc, jt * 16 + l16)] = f2bf(__expf(sv[jt] - m_s[r]));
    }

    // ---- PV (Ps is wave-private: no barrier) ----
    #pragma unroll
    for (int js = 0; js < 2; ++js) {
      bf16x8 pa = *(const bf16x8*)&Ps[w][sw(l16, js * 32 + lh * 8)];
      #pragma unroll
      for (int dt = 0; dt < 4; ++dt)
        o[dt] = __builtin_amdgcn_mfma_f32_16x16x32_bf16(pa, vv[js][dt], o[dt], 0, 0, 0);
      o[4] = __builtin_amdgcn_mfma_f32_16x16x32_bf16(pa, ones, o[4], 0, 0, 0);
    }
  }

  #pragma unroll
  for (int r = 0; r < 4; ++r) {
    float inv = 1.f / o[4][r];
    int gi = i0 + w * 16 + lh * 4 + r;
    #pragma unroll
    for (int dt = 0; dt < 4; ++dt)
      attnout[((size_t)bb * 1024 + gi) * 512 + hh * 64 + dt * 16 + l16] = f2bf(o[dt][r] * inv);
  }
}

extern "C" void kernel_launch(void* const* d_in, const int* in_sizes, int n_in,
                              void* d_out, int out_size, void* d_ws, size_t ws_size,
                              hipStream_t stream) {
  const float* x     = (const float*)d_in[0];
  const float* gamma = (const float*)d_in[1];
  const float* w_qkv = (const float*)d_in[2];
  const float* w_out = (const float*)d_in[3];
  const float* cw0   = (const float*)d_in[4];
  const float* cb0   = (const float*)d_in[5];
  const float* cw1   = (const float*)d_in[6];
  const float* cb1   = (const float*)d_in[7];
  const float* cw2   = (const float*)d_in[8];
  const float* cb2   = (const float*)d_in[9];
  float* out = (float*)d_out;

  char* ws = (char*)d_ws;
  unsigned short* xnT   = (unsigned short*)(ws + 0);          // 8 MB
  unsigned short* wqb   = (unsigned short*)(ws + 8388608);    // 1.5 MB
  unsigned short* wob   = (unsigned short*)(ws + 9961472);    // 0.5 MB
  unsigned short* qT    = (unsigned short*)(ws + 10485760);   // 8 MB
  unsigned short* kT    = (unsigned short*)(ws + 18874368);   // 8 MB
  unsigned short* vB    = (unsigned short*)(ws + 27262976);   // 8 MB
  float*          table = (float*)(ws + 35651584);            // 128 KB
  unsigned short* biasP = (unsigned short*)(ws + 35782656);   // 16 MB
  unsigned short* aout  = (unsigned short*)(ws + 52559872);   // 8 MB

  prep_weights<<<3072, 256, 0, stream>>>(w_qkv, w_out, wqb, wob);
  cpb_table<<<3969, 128, 0, stream>>>(cw0, cb0, cw1, cb1, cw2, cb2, table);
  bias_expand<<<32768, 256, 0, stream>>>(table, biasP);
  ln_kernel<<<256, 256, 0, stream>>>(x, gamma, xnT);
  gemm_bt<0><<<dim3(64, 12), 256, 0, stream>>>(wqb, xnT, qT, kT, vB, nullptr, nullptr);
  attn_kernel<<<dim3(64, 16), 256, 0, stream>>>(qT, kT, vB, biasP, aout);
  gemm_bt<1><<<dim3(64, 4), 256, 0, stream>>>(wob, aout, nullptr, nullptr, nullptr, x, out);
}

// Round 5
// 180.579 us; speedup vs baseline: 1.2946x; 1.2946x over previous
//
#include <hip/hip_runtime.h>
#include <hip/hip_bf16.h>

#define CCH   512
#define BATCH 8
#define NPOS  1024
#define MQKV  1536
#define EPS   1e-5f
#define LOG2E 1.4426950408889634f

typedef __attribute__((ext_vector_type(4))) float f32x4;
typedef __attribute__((ext_vector_type(8))) __bf16 bf16x8;
typedef __attribute__((ext_vector_type(8))) unsigned short u16x8;
typedef __attribute__((ext_vector_type(4))) unsigned short u16x4;

__device__ inline unsigned short f2bf(float f) {
  __hip_bfloat16 h = __float2bfloat16(f);
  return __builtin_bit_cast(unsigned short, h);
}
__device__ inline float bf2f(unsigned short u) {
  return __bfloat162float(__builtin_bit_cast(__hip_bfloat16, u));
}

// LDS xor-swizzle (T2): ushort index within a [row][64] tile.
__device__ inline int sw(int row, int col) { return row * 64 + (col ^ ((row & 7) << 3)); }

// ---------------- 1. weights fp32 -> bf16 (q rows pre-scaled by 0.125*log2e) ----------------
__global__ void prep_weights(const float* __restrict__ wq, const float* __restrict__ wo,
                             unsigned short* __restrict__ wqb, unsigned short* __restrict__ wob) {
  int i = blockIdx.x * 256 + threadIdx.x;
  if (i < MQKV * CCH) {
    float v = wq[i];
    if (i < 512 * CCH) v *= 0.125f * LOG2E;   // scores arrive in log2 domain
    wqb[i] = f2bf(v);
  }
  if (i < CCH * CCH) wob[i] = f2bf(wo[i]);
}

// ---------------- 2. CPB table: [8][63][63], scaled by log2e ----------------
__global__ void cpb_table(const float* __restrict__ w0, const float* __restrict__ b0,
                          const float* __restrict__ w1, const float* __restrict__ b1,
                          const float* __restrict__ w2, const float* __restrict__ b2,
                          float* __restrict__ table) {
  __shared__ float sh1[128];
  __shared__ float sh2[128];
  int d0 = blockIdx.x;               // 0..3968
  int dy = d0 / 63 - 31, dx = d0 % 63 - 31;
  float r0 = (dy > 0 ? 1.f : (dy < 0 ? -1.f : 0.f)) * logf(fabsf((float)dy) + 1.f);
  float r1 = (dx > 0 ? 1.f : (dx < 0 ? -1.f : 0.f)) * logf(fabsf((float)dx) + 1.f);
  int t = threadIdx.x;               // 128
  float h0 = r0 * w0[t * 2 + 0] + r1 * w0[t * 2 + 1] + b0[t];
  sh1[t] = (h0 >= 0.f) ? h0 : 0.1f * h0;
  __syncthreads();
  float a = b1[t];
  #pragma unroll 8
  for (int c = 0; c < 128; ++c) a += sh1[c] * w1[t * 128 + c];
  sh2[t] = (a >= 0.f) ? a : 0.1f * a;
  __syncthreads();
  if (t < 8) {
    float o = b2[t];
    #pragma unroll 8
    for (int c = 0; c < 128; ++c) o += sh2[c] * w2[t * 128 + c];
    table[t * 3969 + d0] = o * LOG2E;
  }
}

// ---------------- 3. expand bias, fragment-permuted: [h][i][jtile(16)][l16*4+jt] ----------------
__global__ void bias_expand(const float* __restrict__ table, unsigned short* __restrict__ biasP) {
  int idx = blockIdx.x * 256 + threadIdx.x;   // 8*1024*1024 total, idx == output address
  int h = idx >> 20;
  int i = (idx >> 10) & 1023;
  int blk = (idx >> 6) & 15;
  int q = idx & 63;
  int l16 = q >> 2, jt = q & 3;
  int j = blk * 64 + jt * 16 + l16;
  int dy = (i >> 5) - (j >> 5) + 31;
  int dx = (i & 31) - (j & 31) + 31;
  biasP[idx] = f2bf(table[h * 3969 + dy * 63 + dx]);
}

// ---------------- 4. channel LayerNorm -> xnT [8192][512] bf16 ----------------
__global__ __launch_bounds__(256) void ln_kernel(const float* __restrict__ x,
                                                 const float* __restrict__ gamma,
                                                 unsigned short* __restrict__ xnT) {
  int t = threadIdx.x;
  int gpos = blockIdx.x * 32 + (t >> 3);      // global position 0..8191
  int b = gpos >> 10, p = gpos & 1023;
  int cl = t & 7;
  const float* xp = x + (size_t)b * CCH * NPOS + p;
  float vals[64];
  float s1 = 0.f, s2 = 0.f;
  #pragma unroll
  for (int j = 0; j < 64; ++j) {
    float v = xp[(size_t)(cl * 64 + j) * NPOS];
    vals[j] = v; s1 += v; s2 += v * v;
  }
  #pragma unroll
  for (int m = 1; m < 8; m <<= 1) { s1 += __shfl_xor(s1, m, 64); s2 += __shfl_xor(s2, m, 64); }
  float mean = s1 * (1.f / 512.f);
  float var = s2 * (1.f / 512.f) - mean * mean;
  float rstd = rsqrtf(var + EPS);
  unsigned short outv[64];
  #pragma unroll
  for (int j = 0; j < 64; ++j) {
    int c = cl * 64 + j;
    outv[j] = f2bf((vals[j] - mean) * rstd * gamma[c]);
  }
  unsigned short* op = xnT + (size_t)gpos * 512 + cl * 64;
  #pragma unroll
  for (int j = 0; j < 8; ++j) *(u16x8*)(op + j * 8) = *(const u16x8*)(outv + j * 8);
}

// ---------------- 5. GEMM C = A * B^T, A[M][512], B[N][512] bf16 ----------------
// MODE 0: qkv epilogue (LDS-bounced coalesced scatter to qT/kT/vB).
// MODE 1: out proj + residual -> f32.
template <int MODE>
__global__ __launch_bounds__(256) void gemm_bt(const unsigned short* __restrict__ Ag,
                                               const unsigned short* __restrict__ Bg,
                                               unsigned short* __restrict__ qT,
                                               unsigned short* __restrict__ kT,
                                               unsigned short* __restrict__ vB,
                                               const float* __restrict__ xres,
                                               float* __restrict__ yout) {
  __shared__ unsigned short smem[2 * 128 * 64];   // As | Bs; reused as 128x128 C-tile
  unsigned short* As = smem;
  unsigned short* Bs = smem + 128 * 64;
  int tid = threadIdx.x;
  int m0 = blockIdx.y * 128, nn0 = blockIdx.x * 128;
  int wave = tid >> 6, lane = tid & 63;
  int wm = wave >> 1, wn = wave & 1;
  int l16 = lane & 15, lh = lane >> 4;
  f32x4 acc[4][4];
  #pragma unroll
  for (int it = 0; it < 4; ++it)
    #pragma unroll
    for (int jt = 0; jt < 4; ++jt) acc[it][jt] = (f32x4){0.f, 0.f, 0.f, 0.f};

  for (int k0 = 0; k0 < 512; k0 += 64) {
    #pragma unroll
    for (int r = 0; r < 4; ++r) {
      int li = r * 2048 + tid * 8;
      int row = li >> 6, col = li & 63;
      *(u16x8*)&As[sw(row, col)] = *(const u16x8*)&Ag[(size_t)(m0 + row) * 512 + k0 + col];
      *(u16x8*)&Bs[sw(row, col)] = *(const u16x8*)&Bg[(size_t)(nn0 + row) * 512 + k0 + col];
    }
    __syncthreads();
    #pragma unroll
    for (int ks = 0; ks < 2; ++ks) {
      int koff = ks * 32 + lh * 8;
      bf16x8 a[4], b[4];
      #pragma unroll
      for (int it = 0; it < 4; ++it) a[it] = *(const bf16x8*)&As[sw(wm * 64 + it * 16 + l16, koff)];
      #pragma unroll
      for (int jt = 0; jt < 4; ++jt) b[jt] = *(const bf16x8*)&Bs[sw(wn * 64 + jt * 16 + l16, koff)];
      #pragma unroll
      for (int it = 0; it < 4; ++it)
        #pragma unroll
        for (int jt = 0; jt < 4; ++jt)
          acc[it][jt] = __builtin_amdgcn_mfma_f32_16x16x32_bf16(a[it], b[jt], acc[it][jt], 0, 0, 0);
    }
    __syncthreads();
  }

  if (MODE == 1) {
    #pragma unroll
    for (int it = 0; it < 4; ++it) {
      int mbase = m0 + wm * 64 + it * 16 + lh * 4;
      #pragma unroll
      for (int jt = 0; jt < 4; ++jt) {
        int nn = nn0 + wn * 64 + jt * 16 + l16;
        int bb = nn >> 10, p = nn & 1023;
        #pragma unroll
        for (int r = 0; r < 4; ++r) {
          size_t addr = ((size_t)bb * 512 + mbase + r) * 1024 + p;
          yout[addr] = acc[it][jt][r] + xres[addr];
        }
      }
    }
  } else {
    // ---- LDS-bounced coalesced epilogue ----
    int by = blockIdx.y;
    int sel = by >> 2;                 // 0:q 1:k 2:v (m0 = by*128, 512 rows per sel)
    int hh0 = (by & 3) * 2;            // first of the two local heads in this m-block
    int bb = nn0 >> 10, p0 = nn0 & 1023;
    unsigned short* Cs = smem;         // 128x128 ushort = 32 KB
    if (sel < 2) {
      // transposed store: Cs[nn][m^k(nn)] so d (part of m) is contiguous on read
      #pragma unroll
      for (int it = 0; it < 4; ++it)
        #pragma unroll
        for (int jt = 0; jt < 4; ++jt) {
          int nnl = wn * 64 + jt * 16 + l16;
          int mb = wm * 64 + it * 16 + lh * 4;
          #pragma unroll
          for (int r = 0; r < 4; ++r)
            Cs[nnl * 128 + ((mb + r) ^ ((nnl & 7) << 4))] = f2bf(acc[it][jt][r]);
        }
      __syncthreads();
      unsigned short* dst = (sel == 0) ? qT : kT;
      // 2048 chunks of 8 ushort: c = [hl(1)][p(7)][ch(3)]
      #pragma unroll
      for (int i = 0; i < 8; ++i) {
        int c = tid + i * 256;
        int hl = c >> 10, p = (c >> 3) & 127, ch = c & 7;
        int mb = hl * 64 + ch * 8;
        u16x8 val = *(u16x8*)&Cs[p * 128 + (mb ^ ((p & 7) << 4))];
        int bh = bb * 8 + hh0 + hl;
        *(u16x8*)&dst[((size_t)bh * 1024 + p0 + p) * 64 + ch * 8] = val;
      }
    } else {
      // row-major store: Cs[m][nn^k(m)] so p (= nn) is contiguous on read
      #pragma unroll
      for (int it = 0; it < 4; ++it)
        #pragma unroll
        for (int jt = 0; jt < 4; ++jt) {
          int nnl = wn * 64 + jt * 16 + l16;
          int mb = wm * 64 + it * 16 + lh * 4;
          #pragma unroll
          for (int r = 0; r < 4; ++r)
            Cs[(mb + r) * 128 + (nnl ^ (((mb + r) & 7) << 4))] = f2bf(acc[it][jt][r]);
        }
      __syncthreads();
      // 2048 chunks: c = [mloc(7)][ch(4)]
      #pragma unroll
      for (int i = 0; i < 8; ++i) {
        int c = tid + i * 256;
        int mloc = c >> 4, ch = c & 15;
        u16x8 val = *(u16x8*)&Cs[mloc * 128 + ((ch * 8) ^ ((mloc & 7) << 4))];
        int d = mloc & 63, hl = mloc >> 6;
        int bh = bb * 8 + hh0 + hl;
        *(u16x8*)&vB[((size_t)bh * 64 + d) * 1024 + p0 + ch * 8] = val;
      }
    }
  }
}

// ---------------- 6. flash attention: LDS-staged, double-buffered, counted-wait barrier ----
// grid x = bh (fastest -> 8 bh per XCD -> 2MB K/V per L2); Q in regs; softmax in log2 domain.
__global__ __launch_bounds__(256) void attn_kernel(const unsigned short* __restrict__ qT,
                                                   const unsigned short* __restrict__ kT,
                                                   const unsigned short* __restrict__ vB,
                                                   const unsigned short* __restrict__ biasP,
                                                   unsigned short* __restrict__ attnout) {
  __shared__ unsigned short Kbuf[2][64 * 64];
  __shared__ unsigned short Vbuf[2][64 * 64];
  __shared__ unsigned short Ps[4][16 * 64];
  int tid = threadIdx.x;
  int bh = blockIdx.x;
  int i0 = blockIdx.y * 64;
  int hh = bh & 7, bb = bh >> 3;
  int w = tid >> 6, lane = tid & 63, l16 = lane & 15, lh = lane >> 4;

  const unsigned short* kbase = kT + (size_t)bh * NPOS * 64;
  const unsigned short* vbase = vB + (size_t)bh * 64 * NPOS;
  const unsigned short* bptr = biasP + (((size_t)hh * 1024 + i0 + w * 16) * 16) * 64 + l16 * 4;

  // Q fragments in registers (one q-row per lane)
  {
  }
  int qrow = i0 + w * 16 + l16;
  const unsigned short* qb = qT + ((size_t)bh * NPOS + qrow) * 64 + lh * 8;
  bf16x8 qreg[2];
  qreg[0] = *(const bf16x8*)&qb[0];
  qreg[1] = *(const bf16x8*)&qb[32];

  // staging geometry: each thread covers (srow, scol) and (srow+32, scol)
  int srow = tid >> 3, scol = (tid & 7) * 8;

  f32x4 o[5];                        // 0..3 output d-fragments, 4 = softmax denominator
  float m_s[4];
  #pragma unroll
  for (int dt = 0; dt < 5; ++dt) o[dt] = (f32x4){0.f, 0.f, 0.f, 0.f};
  #pragma unroll
  for (int r = 0; r < 4; ++r) m_s[r] = -1e30f;

  bf16x8 ones;
  {
    u16x8 tmp = {0x3F80, 0x3F80, 0x3F80, 0x3F80, 0x3F80, 0x3F80, 0x3F80, 0x3F80};
    ones = __builtin_bit_cast(bf16x8, tmp);
  }

  // ---- prologue: stage tile 0 ----
  u16x8 kreg0, kreg1, vreg0, vreg1;
  kreg0 = *(const u16x8*)&kbase[(size_t)srow * 64 + scol];
  kreg1 = *(const u16x8*)&kbase[(size_t)(srow + 32) * 64 + scol];
  vreg0 = *(const u16x8*)&vbase[(size_t)srow * 1024 + scol];
  vreg1 = *(const u16x8*)&vbase[(size_t)(srow + 32) * 1024 + scol];
  *(u16x8*)&Kbuf[0][sw(srow, scol)] = kreg0;
  *(u16x8*)&Kbuf[0][sw(srow + 32, scol)] = kreg1;
  *(u16x8*)&Vbuf[0][sw(srow, scol)] = vreg0;
  *(u16x8*)&Vbuf[0][sw(srow + 32, scol)] = vreg1;

  #pragma unroll 1
  for (int t = 0; t < 16; ++t) {
    int j0 = t * 64;
    // ---- issue next tile's global loads (stay in flight across the barrier) ----
    if (t < 15) {
      int j1 = j0 + 64;
      kreg0 = *(const u16x8*)&kbase[(size_t)(j1 + srow) * 64 + scol];
      kreg1 = *(const u16x8*)&kbase[(size_t)(j1 + srow + 32) * 64 + scol];
      vreg0 = *(const u16x8*)&vbase[(size_t)srow * 1024 + j1 + scol];
      vreg1 = *(const u16x8*)&vbase[(size_t)(srow + 32) * 1024 + j1 + scol];
    }
    // LDS-only drain + raw barrier: in-flight global loads are NOT waited here
    asm volatile("s_waitcnt lgkmcnt(0)" ::: "memory");
    __builtin_amdgcn_s_barrier();

    const unsigned short* Ks = Kbuf[t & 1];
    const unsigned short* Vs = Vbuf[t & 1];

    // ---- bias loads first: overlap QK^T MFMAs ----
    u16x4 bv4[4];
    #pragma unroll
    for (int r = 0; r < 4; ++r) bv4[r] = *(const u16x4*)&bptr[(lh * 4 + r) * 1024 + j0];

    // ---- QK^T ----
    f32x4 s[4];
    #pragma unroll
    for (int jt = 0; jt < 4; ++jt) s[jt] = (f32x4){0.f, 0.f, 0.f, 0.f};
    #pragma unroll
    for (int ks = 0; ks < 2; ++ks) {
      int koff = ks * 32 + lh * 8;
      #pragma unroll
      for (int jt = 0; jt < 4; ++jt) {
        bf16x8 bk = *(const bf16x8*)&Ks[sw(jt * 16 + l16, koff)];
        s[jt] = __builtin_amdgcn_mfma_f32_16x16x32_bf16(qreg[ks], bk, s[jt], 0, 0, 0);
      }
    }

    // ---- online softmax in log2 domain, defer-max (THR = 8*log2e) ----
    #pragma unroll
    for (int r = 0; r < 4; ++r) {
      int rloc = lh * 4 + r;
      float sv[4];
      #pragma unroll
      for (int jt = 0; jt < 4; ++jt) sv[jt] = s[jt][r] + bf2f(bv4[r][jt]);
      float tmax = fmaxf(fmaxf(sv[0], sv[1]), fmaxf(sv[2], sv[3]));
      #pragma unroll
      for (int mm = 1; mm < 16; mm <<= 1) tmax = fmaxf(tmax, __shfl_xor(tmax, mm, 64));
      if (!__all(tmax <= m_s[r] + 11.5415603f)) {
        float mnew = fmaxf(m_s[r], tmax);
        float corr = __builtin_amdgcn_exp2f(m_s[r] - mnew);
        m_s[r] = mnew;
        #pragma unroll
        for (int dt = 0; dt < 5; ++dt) o[dt][r] *= corr;
      }
      #pragma unroll
      for (int jt = 0; jt < 4; ++jt)
        Ps[w][sw(rloc, jt * 16 + l16)] = f2bf(__builtin_amdgcn_exp2f(sv[jt] - m_s[r]));
    }

    // ---- PV (Ps is wave-private: no barrier) ----
    #pragma unroll
    for (int js = 0; js < 2; ++js) {
      int koff = js * 32 + lh * 8;
      bf16x8 pa = *(const bf16x8*)&Ps[w][sw(l16, koff)];
      #pragma unroll
      for (int dt = 0; dt < 4; ++dt) {
        bf16x8 vb = *(const bf16x8*)&Vs[sw(dt * 16 + l16, koff)];
        o[dt] = __builtin_amdgcn_mfma_f32_16x16x32_bf16(pa, vb, o[dt], 0, 0, 0);
      }
      o[4] = __builtin_amdgcn_mfma_f32_16x16x32_bf16(pa, ones, o[4], 0, 0, 0);
    }

    // ---- write next tile into the other buffer (vmcnt wait auto-inserted here) ----
    if (t < 15) {
      unsigned short* Kd = Kbuf[(t + 1) & 1];
      unsigned short* Vd = Vbuf[(t + 1) & 1];
      *(u16x8*)&Kd[sw(srow, scol)] = kreg0;
      *(u16x8*)&Kd[sw(srow + 32, scol)] = kreg1;
      *(u16x8*)&Vd[sw(srow, scol)] = vreg0;
      *(u16x8*)&Vd[sw(srow + 32, scol)] = vreg1;
    }
  }

  #pragma unroll
  for (int r = 0; r < 4; ++r) {
    float inv = 1.f / o[4][r];
    int gi = i0 + w * 16 + lh * 4 + r;
    #pragma unroll
    for (int dt = 0; dt < 4; ++dt)
      attnout[((size_t)bb * 1024 + gi) * 512 + hh * 64 + dt * 16 + l16] = f2bf(o[dt][r] * inv);
  }
}

extern "C" void kernel_launch(void* const* d_in, const int* in_sizes, int n_in,
                              void* d_out, int out_size, void* d_ws, size_t ws_size,
                              hipStream_t stream) {
  const float* x     = (const float*)d_in[0];
  const float* gamma = (const float*)d_in[1];
  const float* w_qkv = (const float*)d_in[2];
  const float* w_out = (const float*)d_in[3];
  const float* cw0   = (const float*)d_in[4];
  const float* cb0   = (const float*)d_in[5];
  const float* cw1   = (const float*)d_in[6];
  const float* cb1   = (const float*)d_in[7];
  const float* cw2   = (const float*)d_in[8];
  const float* cb2   = (const float*)d_in[9];
  float* out = (float*)d_out;

  char* ws = (char*)d_ws;
  unsigned short* xnT   = (unsigned short*)(ws + 0);          // 8 MB
  unsigned short* wqb   = (unsigned short*)(ws + 8388608);    // 1.5 MB
  unsigned short* wob   = (unsigned short*)(ws + 9961472);    // 0.5 MB
  unsigned short* qT    = (unsigned short*)(ws + 10485760);   // 8 MB
  unsigned short* kT    = (unsigned short*)(ws + 18874368);   // 8 MB
  unsigned short* vB    = (unsigned short*)(ws + 27262976);   // 8 MB
  float*          table = (float*)(ws + 35651584);            // 128 KB
  unsigned short* biasP = (unsigned short*)(ws + 35782656);   // 16 MB
  unsigned short* aout  = (unsigned short*)(ws + 52559872);   // 8 MB

  prep_weights<<<3072, 256, 0, stream>>>(w_qkv, w_out, wqb, wob);
  cpb_table<<<3969, 128, 0, stream>>>(cw0, cb0, cw1, cb1, cw2, cb2, table);
  bias_expand<<<32768, 256, 0, stream>>>(table, biasP);
  ln_kernel<<<256, 256, 0, stream>>>(x, gamma, xnT);
  gemm_bt<0><<<dim3(64, 12), 256, 0, stream>>>(wqb, xnT, qT, kT, vB, nullptr, nullptr);
  attn_kernel<<<dim3(64, 16), 256, 0, stream>>>(qT, kT, vB, biasP, aout);
  gemm_bt<1><<<dim3(64, 4), 256, 0, stream>>>(wob, aout, nullptr, nullptr, nullptr, x, out);
}